// Round 13
// baseline (174.954 us; speedup 1.0000x reference)
//
#include <hip/hip_runtime.h>
#include <hip/hip_fp16.h>

#define NPTS  8192
#define DDIM  384
#define NC    52
#define NCELL (NC * NC)           // 2704
#define GY0   -5.2005f
#define GHINV 4.99750124937531f   // 1/0.2001
#define TROWS 16
#define NBLK  (NPTS / TROWS)      // 512
#define UCAP  2048

// ws layout (bytes):
//  csS       half2[NPTS*DDIM]  @ 0          12582912   (sorted-order (cos,sin), row = 1536 B)
//  xyS       float2[NPTS]      @ 12582912      65536
//  perm      int[NPTS]         @ 12648448      32768
//  cellStart int[NCELL+1]      @ 12681216      12288

__device__ __forceinline__ int cell_of(float a, float b)
{
    int c1 = (int)floorf((a - GY0) * GHINV);
    int c2 = (int)floorf((b - GY0) * GHINV);
    c1 = min(NC - 1, max(0, c1));
    c2 = min(NC - 1, max(0, c2));
    return c1 * NC + c2;
}

// Fused setup: bin + exclusive-scan + scatter, one workgroup.
__global__ __launch_bounds__(1024)
void setup_kernel(const float* __restrict__ pts, int* __restrict__ cellStart,
                  int* __restrict__ perm, float2* __restrict__ xyS)
{
    __shared__ int cnt[NCELL];
    __shared__ int scanbuf[1024];
    const int t = threadIdx.x;

    for (int c = t; c < NCELL; c += 1024) cnt[c] = 0;
    __syncthreads();
    for (int n = t; n < NPTS; n += 1024)
        atomicAdd(&cnt[cell_of(pts[3 * n + 1], pts[3 * n + 2])], 1);
    __syncthreads();

    const int base = t * 3;                 // 1024*3 >= 2704
    int s = 0;
    for (int c = base; c < base + 3 && c < NCELL; ++c) s += cnt[c];
    scanbuf[t] = s;
    __syncthreads();
    for (int off = 1; off < 1024; off <<= 1) {
        int v = (t >= off) ? scanbuf[t - off] : 0;
        __syncthreads();
        scanbuf[t] += v;
        __syncthreads();
    }
    int acc = scanbuf[t] - s;               // exclusive prefix
    for (int c = base; c < base + 3 && c < NCELL; ++c) {
        int v = cnt[c];
        cellStart[c] = acc;
        cnt[c] = acc;                       // becomes scatter cursor
        acc += v;
    }
    if (t == 0) cellStart[NCELL] = NPTS;
    __syncthreads();

    for (int n = t; n < NPTS; n += 1024) {
        float a = pts[3 * n + 1];
        float b = pts[3 * n + 2];
        int pos = atomicAdd(&cnt[cell_of(a, b)], 1);
        perm[pos] = n;
        xyS[pos]  = make_float2(a, b);
    }
}

__global__ __launch_bounds__(DDIM)
void cs_kernel(const float* __restrict__ pts, const float* __restrict__ A,
               const int* __restrict__ perm, __half2* __restrict__ csS)
{
    const int r = blockIdx.x;
    const int t = threadIdx.x;
    const int n = perm[r];
    const float p0 = pts[3 * n + 0];
    const float p1 = pts[3 * n + 1];
    const float p2 = pts[3 * n + 2];
    const float pa = fmaf(p2, A[2 * DDIM + t],
                     fmaf(p1, A[DDIM + t], __fmul_rn(p0, A[t])));
    float s, c;
    sincosf(pa, &s, &c);
    csS[r * DDIM + t] = __floats2half2_rn(c, s);
}

__global__ __launch_bounds__(DDIM)
void tile_kernel(const __half2* __restrict__ csS, const float2* __restrict__ xyS,
                 const int* __restrict__ perm, const int* __restrict__ cellStart,
                 float* __restrict__ out)
{
    __shared__ int    ulist[UCAP];
    __shared__ int    ubits[UCAP];
    __shared__ int    ucnt;
    __shared__ float2 rxy[TROWS];
    __shared__ float  rsq[TROWS];
    __shared__ int    pr[TROWS];
    __shared__ float  red[TROWS][8];
    __shared__ float  scl[TROWS];

    // balance + locality swizzle: XCD x (bid%8) gets 8 runs of 8 blocks
    const int bid = blockIdx.x;
    const int xcd = bid & 7, q8 = bid >> 3;
    const int ch  = q8 >> 3, w = q8 & 7;
    const int blk = 64 * ch + 8 * xcd + w;      // bijective on [0,512)
    const int r0  = blk * TROWS;

    const int t = threadIdx.x;
    if (t == 0) ucnt = 0;
    if (t < TROWS) {
        float2 p = xyS[r0 + t];
        rxy[t] = p;
        rsq[t] = __fadd_rn(__fmul_rn(p.x, p.x), __fmul_rn(p.y, p.y));
        pr[t]  = perm[r0 + t];
    }
    __syncthreads();

    // dilated cell span over the 16 rows (superset of each row's 3x3)
    int c1lo = NC - 1, c1hi = 0, c2lo = NC - 1, c2hi = 0;
    #pragma unroll
    for (int rr = 0; rr < TROWS; ++rr) {
        int c1 = (int)floorf((rxy[rr].x - GY0) * GHINV);
        int c2 = (int)floorf((rxy[rr].y - GY0) * GHINV);
        c1 = min(NC - 1, max(0, c1)); c2 = min(NC - 1, max(0, c2));
        c1lo = min(c1lo, c1); c1hi = max(c1hi, c1);
        c2lo = min(c2lo, c2); c2hi = max(c2hi, c2);
    }
    c1lo = max(0, c1lo - 1); c1hi = min(NC - 1, c1hi + 1);
    c2lo = max(0, c2lo - 1); c2hi = min(NC - 1, c2hi + 1);

    // scan: exact fp32 J test (bit-identical formula) vs all 16 rows at once
    for (int cr = c1lo; cr <= c1hi; ++cr) {
        const int qlo = cellStart[cr * NC + c2lo];
        const int qhi = cellStart[cr * NC + c2hi + 1];
        for (int qq = qlo + t; qq < qhi; qq += DDIM) {
            const float2 pj  = xyS[qq];
            const float  sqj = __fadd_rn(__fmul_rn(pj.x, pj.x), __fmul_rn(pj.y, pj.y));
            int bits = 0;
            #pragma unroll
            for (int rr = 0; rr < TROWS; ++rr) {
                const float dot = fmaf(rxy[rr].y, pj.y, __fmul_rn(rxy[rr].x, pj.x));
                const float d2  = __fsub_rn(__fadd_rn(rsq[rr], sqj), __fmul_rn(2.0f, dot));
                if (d2 < 0.04f) bits |= (1 << rr);
            }
            if (bits) {
                int p = atomicAdd(&ucnt, 1);
                if (p < UCAP) { ulist[p] = qq; ubits[p] = bits; }
            }
        }
    }
    __syncthreads();
    const int U = ucnt < UCAP ? ucnt : UCAP;

    // gather: each union row loaded ONCE, fanned out to 16 fp32 accumulators
    float accR[TROWS], accI[TROWS];
    #pragma unroll
    for (int rr = 0; rr < TROWS; ++rr) { accR[rr] = 0.f; accI[rr] = 0.f; }

    const __half2* colp = csS + t;              // thread owns column t
    int u = 0;
    for (; u + 4 <= U; u += 4) {
        const int q0 = ulist[u + 0], q1 = ulist[u + 1];
        const int q2 = ulist[u + 2], q3 = ulist[u + 3];
        const int b0 = __builtin_amdgcn_readfirstlane(ubits[u + 0]);
        const int b1 = __builtin_amdgcn_readfirstlane(ubits[u + 1]);
        const int b2 = __builtin_amdgcn_readfirstlane(ubits[u + 2]);
        const int b3 = __builtin_amdgcn_readfirstlane(ubits[u + 3]);
        const float2 v0 = __half22float2(colp[q0 * DDIM]);
        const float2 v1 = __half22float2(colp[q1 * DDIM]);
        const float2 v2 = __half22float2(colp[q2 * DDIM]);
        const float2 v3 = __half22float2(colp[q3 * DDIM]);
        #pragma unroll
        for (int rr = 0; rr < TROWS; ++rr) {
            if (b0 & (1 << rr)) { accR[rr] += v0.x; accI[rr] += v0.y; }
            if (b1 & (1 << rr)) { accR[rr] += v1.x; accI[rr] += v1.y; }
            if (b2 & (1 << rr)) { accR[rr] += v2.x; accI[rr] += v2.y; }
            if (b3 & (1 << rr)) { accR[rr] += v3.x; accI[rr] += v3.y; }
        }
    }
    for (; u < U; ++u) {
        const int qd = ulist[u];
        const int bd = __builtin_amdgcn_readfirstlane(ubits[u]);
        const float2 v = __half22float2(colp[qd * DDIM]);
        #pragma unroll
        for (int rr = 0; rr < TROWS; ++rr)
            if (bd & (1 << rr)) { accR[rr] += v.x; accI[rr] += v.y; }
    }

    // per-row norms (16 block reductions)
    const int lane = t & 63, wv = t >> 6;
    #pragma unroll
    for (int rr = 0; rr < TROWS; ++rr) {
        float p = fmaf(accR[rr], accR[rr], accI[rr] * accI[rr]);
        #pragma unroll
        for (int off = 32; off > 0; off >>= 1) p += __shfl_down(p, off, 64);
        if (lane == 0) red[rr][wv] = p;
    }
    __syncthreads();
    if (t < TROWS) {
        float tot = 0.f;
        #pragma unroll
        for (int wq = 0; wq < 6; ++wq) tot += red[t][wq];
        scl[t] = 19.59591794226543f / sqrtf(tot);   // sqrt(384)/nrm
    }
    __syncthreads();

    // rotate by conj(e^{i pa_i}) (hot table row) and write real part
    #pragma unroll
    for (int rr = 0; rr < TROWS; ++rr) {
        const float2 ci = __half22float2(csS[(r0 + rr) * DDIM + t]);
        const float  Gr = fmaf(accR[rr], ci.x, accI[rr] * ci.y);
        out[pr[rr] * DDIM + t] = Gr * scl[rr];
    }
}

extern "C" void kernel_launch(void* const* d_in, const int* in_sizes, int n_in,
                              void* d_out, int out_size, void* d_ws, size_t ws_size,
                              hipStream_t stream)
{
    const float* pts = (const float*)d_in[0];
    const float* A   = (const float*)d_in[1];
    if (n_in >= 2 && in_sizes[0] == 3 * DDIM && in_sizes[1] == NPTS * 3) {
        pts = (const float*)d_in[1];
        A   = (const float*)d_in[0];
    }
    char* ws = (char*)d_ws;
    __half2* csS       = (__half2*)(ws + 0);
    float2*  xyS       = (float2*)(ws + 12582912);
    int*     perm      = (int*)(ws + 12648448);
    int*     cellStart = (int*)(ws + 12681216);
    float*   out       = (float*)d_out;

    setup_kernel<<<1, 1024, 0, stream>>>(pts, cellStart, perm, xyS);
    cs_kernel<<<NPTS, DDIM, 0, stream>>>(pts, A, perm, csS);
    tile_kernel<<<NBLK, DDIM, 0, stream>>>(csS, xyS, perm, cellStart, out);
}

// Round 14
// 97.262 us; speedup vs baseline: 1.7988x; 1.7988x over previous
//
#include <hip/hip_runtime.h>
#include <hip/hip_fp16.h>

#define NPTS  8192
#define DDIM  384
#define HCAP  1024
#define NC    52
#define NCELL (NC * NC)           // 2704
#define GY0   -5.2005f
#define GHINV 4.99750124937531f   // 1/0.2001

// ws layout (bytes):
//  csS       half2[NPTS*DDIM]  @ 0         12582912   (sorted-order cos/sin, row = 1536 B)
//  xyS       float2[NPTS]      @ 12582912     65536
//  perm      int[NPTS]         @ 12648448     32768
//  cellStart int[NCELL+1]      @ 12681216     12288

__device__ __forceinline__ int cell_of(float a, float b)
{
    int c1 = (int)floorf((a - GY0) * GHINV);
    int c2 = (int)floorf((b - GY0) * GHINV);
    c1 = min(NC - 1, max(0, c1));
    c2 = min(NC - 1, max(0, c2));
    return c1 * NC + c2;
}

__device__ __forceinline__ __half2 u2h(unsigned u)
{
    union { unsigned u; __half2 h; } v; v.u = u; return v.h;
}
__device__ __forceinline__ unsigned h2u(__half2 h)
{
    union { unsigned u; __half2 h; } v; v.h = h; return v.u;
}

// Fused setup: bin + exclusive-scan + scatter, one workgroup (proven in R13).
__global__ __launch_bounds__(1024)
void setup_kernel(const float* __restrict__ pts, int* __restrict__ cellStart,
                  int* __restrict__ perm, float2* __restrict__ xyS)
{
    __shared__ int cnt[NCELL];
    __shared__ int scanbuf[1024];
    const int t = threadIdx.x;

    for (int c = t; c < NCELL; c += 1024) cnt[c] = 0;
    __syncthreads();
    for (int n = t; n < NPTS; n += 1024)
        atomicAdd(&cnt[cell_of(pts[3 * n + 1], pts[3 * n + 2])], 1);
    __syncthreads();

    const int base = t * 3;                 // 1024*3 >= 2704
    int s = 0;
    for (int c = base; c < base + 3 && c < NCELL; ++c) s += cnt[c];
    scanbuf[t] = s;
    __syncthreads();
    for (int off = 1; off < 1024; off <<= 1) {
        int v = (t >= off) ? scanbuf[t - off] : 0;
        __syncthreads();
        scanbuf[t] += v;
        __syncthreads();
    }
    int acc = scanbuf[t] - s;               // exclusive prefix
    for (int c = base; c < base + 3 && c < NCELL; ++c) {
        int v = cnt[c];
        cellStart[c] = acc;
        cnt[c] = acc;                       // becomes scatter cursor
        acc += v;
    }
    if (t == 0) cellStart[NCELL] = NPTS;
    __syncthreads();

    for (int n = t; n < NPTS; n += 1024) {
        float a = pts[3 * n + 1];
        float b = pts[3 * n + 2];
        int pos = atomicAdd(&cnt[cell_of(a, b)], 1);
        perm[pos] = n;
        xyS[pos]  = make_float2(a, b);
    }
}

__global__ __launch_bounds__(DDIM)
void cs_kernel(const float* __restrict__ pts, const float* __restrict__ A,
               const int* __restrict__ perm, __half2* __restrict__ csS)
{
    const int r = blockIdx.x;
    const int t = threadIdx.x;
    const int n = perm[r];
    const float p0 = pts[3 * n + 0];
    const float p1 = pts[3 * n + 1];
    const float p2 = pts[3 * n + 2];
    const float pa = fmaf(p2, A[2 * DDIM + t],
                     fmaf(p1, A[DDIM + t], __fmul_rn(p0, A[t])));
    float s, c;
    sincosf(pa, &s, &c);
    csS[r * DDIM + t] = __floats2half2_rn(c, s);
}

__global__ __launch_bounds__(DDIM)
void row_kernel(const __half2* __restrict__ csS, const float2* __restrict__ xyS,
                const int* __restrict__ perm, const int* __restrict__ cellStart,
                float* __restrict__ out)
{
    __shared__ int   hits[HCAP];
    __shared__ int   hcnt;
    __shared__ uint2 partl[6][64][3];
    __shared__ float red[6];

    // balance-preserving XCD swizzle: 64 chunks of 128 sorted rows
    const int bid = blockIdx.x;
    const int xcd = bid & 7, q = bid >> 3;
    const int ch  = q >> 7, w = q & 127;
    const int r   = (((ch << 3) + xcd) << 7) + w;

    const int t  = threadIdx.x;
    const int ks = t >> 6;      // wave id 0..5  (wave-uniform)
    const int cg = t & 63;      // lane: owns cols 6cg..6cg+5

    if (t == 0) hcnt = 0;
    __syncthreads();

    const float2 me  = xyS[r];
    const float  xi  = me.x;
    const float  yi  = me.y;
    const float  sqi = __fadd_rn(__fmul_rn(xi, xi), __fmul_rn(yi, yi));

    int c1 = (int)floorf((xi - GY0) * GHINV);
    int c2 = (int)floorf((yi - GY0) * GHINV);
    c1 = min(NC - 1, max(0, c1));
    c2 = min(NC - 1, max(0, c2));
    const int c1lo = max(0, c1 - 1), c1hi = min(NC - 1, c1 + 1);
    const int c2lo = max(0, c2 - 1), c2hi = min(NC - 1, c2 + 1);

    for (int cr = c1lo; cr <= c1hi; ++cr) {
        const int qlo = cellStart[cr * NC + c2lo];
        const int qhi = cellStart[cr * NC + c2hi + 1];
        for (int qq = qlo + t; qq < qhi; qq += DDIM) {
            const float2 pj  = xyS[qq];
            const float  sqj = __fadd_rn(__fmul_rn(pj.x, pj.x), __fmul_rn(pj.y, pj.y));
            const float  dot = fmaf(yi, pj.y, __fmul_rn(xi, pj.x));
            const float  d2  = __fsub_rn(__fadd_rn(sqi, sqj), __fmul_rn(2.0f, dot));
            if (d2 < 0.04f) {                       // exact fp32 J test (unchanged)
                int p = atomicAdd(&hcnt, 1);
                if (p < HCAP) hits[p] = qq;
            }
        }
    }
    __syncthreads();
    const int m = hcnt < HCAP ? hcnt : HCAP;

    // gather: slot ks takes rows k+ks (k step 6); thread covers 6 cols (24 B)
    // via 3 SGPR-base 8B loads; 4-row unroll -> 12 independent loads in flight
    const char* base = (const char*)csS;
    const int   b0   = cg * 24;

    __half2 a0 = u2h(0), a1 = u2h(0), a2 = u2h(0),
            a3 = u2h(0), a4 = u2h(0), a5 = u2h(0);
    int k = 0;
    for (; k + 24 <= m; k += 24) {
        const int jA = __builtin_amdgcn_readfirstlane(hits[k + ks]);
        const int jB = __builtin_amdgcn_readfirstlane(hits[k + 6 + ks]);
        const int jC = __builtin_amdgcn_readfirstlane(hits[k + 12 + ks]);
        const int jD = __builtin_amdgcn_readfirstlane(hits[k + 18 + ks]);
        const char* rA = base + jA * 1536 + b0;
        const char* rB = base + jB * 1536 + b0;
        const char* rC = base + jC * 1536 + b0;
        const char* rD = base + jD * 1536 + b0;
        const uint2 wA0 = *(const uint2*)(rA);
        const uint2 wA1 = *(const uint2*)(rA + 8);
        const uint2 wA2 = *(const uint2*)(rA + 16);
        const uint2 wB0 = *(const uint2*)(rB);
        const uint2 wB1 = *(const uint2*)(rB + 8);
        const uint2 wB2 = *(const uint2*)(rB + 16);
        const uint2 wC0 = *(const uint2*)(rC);
        const uint2 wC1 = *(const uint2*)(rC + 8);
        const uint2 wC2 = *(const uint2*)(rC + 16);
        const uint2 wD0 = *(const uint2*)(rD);
        const uint2 wD1 = *(const uint2*)(rD + 8);
        const uint2 wD2 = *(const uint2*)(rD + 16);
        a0 = __hadd2(a0, u2h(wA0.x)); a1 = __hadd2(a1, u2h(wA0.y));
        a2 = __hadd2(a2, u2h(wA1.x)); a3 = __hadd2(a3, u2h(wA1.y));
        a4 = __hadd2(a4, u2h(wA2.x)); a5 = __hadd2(a5, u2h(wA2.y));
        a0 = __hadd2(a0, u2h(wB0.x)); a1 = __hadd2(a1, u2h(wB0.y));
        a2 = __hadd2(a2, u2h(wB1.x)); a3 = __hadd2(a3, u2h(wB1.y));
        a4 = __hadd2(a4, u2h(wB2.x)); a5 = __hadd2(a5, u2h(wB2.y));
        a0 = __hadd2(a0, u2h(wC0.x)); a1 = __hadd2(a1, u2h(wC0.y));
        a2 = __hadd2(a2, u2h(wC1.x)); a3 = __hadd2(a3, u2h(wC1.y));
        a4 = __hadd2(a4, u2h(wC2.x)); a5 = __hadd2(a5, u2h(wC2.y));
        a0 = __hadd2(a0, u2h(wD0.x)); a1 = __hadd2(a1, u2h(wD0.y));
        a2 = __hadd2(a2, u2h(wD1.x)); a3 = __hadd2(a3, u2h(wD1.y));
        a4 = __hadd2(a4, u2h(wD2.x)); a5 = __hadd2(a5, u2h(wD2.y));
    }
    for (; k + 12 <= m; k += 12) {
        const int jA = __builtin_amdgcn_readfirstlane(hits[k + ks]);
        const int jB = __builtin_amdgcn_readfirstlane(hits[k + 6 + ks]);
        const char* rA = base + jA * 1536 + b0;
        const char* rB = base + jB * 1536 + b0;
        const uint2 wA0 = *(const uint2*)(rA);
        const uint2 wA1 = *(const uint2*)(rA + 8);
        const uint2 wA2 = *(const uint2*)(rA + 16);
        const uint2 wB0 = *(const uint2*)(rB);
        const uint2 wB1 = *(const uint2*)(rB + 8);
        const uint2 wB2 = *(const uint2*)(rB + 16);
        a0 = __hadd2(a0, u2h(wA0.x)); a1 = __hadd2(a1, u2h(wA0.y));
        a2 = __hadd2(a2, u2h(wA1.x)); a3 = __hadd2(a3, u2h(wA1.y));
        a4 = __hadd2(a4, u2h(wA2.x)); a5 = __hadd2(a5, u2h(wA2.y));
        a0 = __hadd2(a0, u2h(wB0.x)); a1 = __hadd2(a1, u2h(wB0.y));
        a2 = __hadd2(a2, u2h(wB1.x)); a3 = __hadd2(a3, u2h(wB1.y));
        a4 = __hadd2(a4, u2h(wB2.x)); a5 = __hadd2(a5, u2h(wB2.y));
    }
    for (; k < m; k += 6) {
        if (k + ks < m) {                            // wave-uniform
            const int j = __builtin_amdgcn_readfirstlane(hits[k + ks]);
            const char* rA = base + j * 1536 + b0;
            const uint2 wA0 = *(const uint2*)(rA);
            const uint2 wA1 = *(const uint2*)(rA + 8);
            const uint2 wA2 = *(const uint2*)(rA + 16);
            a0 = __hadd2(a0, u2h(wA0.x)); a1 = __hadd2(a1, u2h(wA0.y));
            a2 = __hadd2(a2, u2h(wA1.x)); a3 = __hadd2(a3, u2h(wA1.y));
            a4 = __hadd2(a4, u2h(wA2.x)); a5 = __hadd2(a5, u2h(wA2.y));
        }
    }

    partl[ks][cg][0] = make_uint2(h2u(a0), h2u(a1));
    partl[ks][cg][1] = make_uint2(h2u(a2), h2u(a3));
    partl[ks][cg][2] = make_uint2(h2u(a4), h2u(a5));
    __syncthreads();

    // fold 6 slots: thread t owns column t
    const int sc = t / 6, comp = t % 6;
    float re = 0.f, im = 0.f;
    #pragma unroll
    for (int s = 0; s < 6; ++s) {
        const uint2 ww = partl[s][sc][comp >> 1];
        const float2 f = __half22float2(u2h((comp & 1) ? ww.y : ww.x));
        re += f.x; im += f.y;
    }

    // row norm
    float p = re * re + im * im;
    #pragma unroll
    for (int off = 32; off > 0; off >>= 1) p += __shfl_down(p, off, 64);
    if ((t & 63) == 0) red[t >> 6] = p;
    __syncthreads();
    const float tot   = (red[0] + red[1]) + (red[2] + red[3]) + (red[4] + red[5]);
    const float scale = 19.59591794226543f / sqrtf(tot);   // sqrt(384)/nrm

    // rotation by conj(e^{i pa_i}) using the (L2-hot) table row itself
    const float2 ci = __half22float2(csS[r * DDIM + t]);
    const float  Gr = fmaf(re, ci.x, im * ci.y);

    out[perm[r] * DDIM + t] = Gr * scale;
}

extern "C" void kernel_launch(void* const* d_in, const int* in_sizes, int n_in,
                              void* d_out, int out_size, void* d_ws, size_t ws_size,
                              hipStream_t stream)
{
    const float* pts = (const float*)d_in[0];
    const float* A   = (const float*)d_in[1];
    if (n_in >= 2 && in_sizes[0] == 3 * DDIM && in_sizes[1] == NPTS * 3) {
        pts = (const float*)d_in[1];
        A   = (const float*)d_in[0];
    }
    char* ws = (char*)d_ws;
    __half2* csS       = (__half2*)(ws + 0);
    float2*  xyS       = (float2*)(ws + 12582912);
    int*     perm      = (int*)(ws + 12648448);
    int*     cellStart = (int*)(ws + 12681216);
    float*   out       = (float*)d_out;

    setup_kernel<<<1, 1024, 0, stream>>>(pts, cellStart, perm, xyS);
    cs_kernel<<<NPTS, DDIM, 0, stream>>>(pts, A, perm, csS);
    row_kernel<<<NPTS, DDIM, 0, stream>>>(csS, xyS, perm, cellStart, out);
}